// Round 3
// baseline (235.976 us; speedup 1.0000x reference)
//
#include <hip/hip_runtime.h>
#include <hip/hip_bf16.h>
#include <cstdint>
#include <cstddef>

// Problem constants
#define B_ 64
#define S_ 4096
#define D_ 256
#define BM 64                   // rows per tile
#define TPB 1024                // 16 waves
#define TILES_PER_BLOCK 16
#define GRID 256                // 1 block per CU; 256*16*64 = 262144 rows
#define BLKS_PER_B (S_ / BM)    // 64 tiles per batch

typedef __attribute__((ext_vector_type(8))) short short8;
typedef __attribute__((ext_vector_type(4))) float f32x4;
typedef __attribute__((ext_vector_type(4))) float f4;

__device__ __forceinline__ short f2bf(float f) {
  union { float f; uint32_t u; } v; v.f = f;
  uint32_t r = v.u + 0x7FFFu + ((v.u >> 16) & 1u);   // RNE
  return (short)(r >> 16);
}

__device__ __forceinline__ float fast_tanh(float z) {
  // tanh(z) = 1 - 2/(e^{2z}+1); overflow-safe
  return 1.0f - 2.0f / (__expf(2.0f * z) + 1.0f);
}

// Kernel 0: Wt[n][k] = bf16(W[k][n]) via LDS tile transpose. grid 16, 256 thr.
__global__ void k_pack(const float* __restrict__ W, short* __restrict__ wt) {
  __shared__ float tile[64][65];
  int t = blockIdx.x, ti = t >> 2, tj = t & 3;
  int tid = threadIdx.x;
#pragma unroll
  for (int i = 0; i < 16; ++i) {
    int idx = i * 256 + tid;
    int r = idx >> 6, c = idx & 63;
    tile[c][r] = W[(ti * 64 + r) * 256 + tj * 64 + c];
  }
  __syncthreads();
#pragma unroll
  for (int i = 0; i < 16; ++i) {
    int idx = i * 256 + tid;
    int r = idx >> 6, c = idx & 63;
    wt[(tj * 64 + r) * 256 + ti * 64 + c] = f2bf(tile[r][c]);
  }
}

// Kernel 1: persistent blocks. B (wt) in registers per wave (col-split);
// A (x tiles) double-buffered in swizzled LDS, prefetched one tile ahead.
__global__ __launch_bounds__(TPB)
void k_scores(const float* __restrict__ x, const short* __restrict__ wt,
              const float* __restrict__ bias, const float* __restrict__ u,
              float* __restrict__ ws_scores, float* __restrict__ ws_m,
              float* __restrict__ ws_l, float* __restrict__ ws_c) {
  __shared__ __align__(16) short lsA[2][BM * D_];   // 2 x 32 KB, XOR-swizzled
  __shared__ float score_part[BM][8];               // per-row, per-col-group partials
  __shared__ float e_lds[BM];
  __shared__ float ctx_part[4][D_];

  const int tid  = threadIdx.x;
  const int lane = tid & 63;
  const int wv   = tid >> 6;        // 0..15
  const int cg   = wv & 7;          // col group: cols cg*32 .. +31
  const int rg   = wv >> 3;         // row group: rows rg*32 .. +31
  const int cl   = lane & 15;
  const int gr   = lane >> 4;       // 0..3
  const int swzr = (cl & 7) << 4;   // row-XOR for A reads (row&7 == cl&7)

  // ---- B in registers: bfr{0,1}[kf], cols cg*32 + nf*16 + cl, k = kf*32+gr*8
  short8 bfr0[8], bfr1[8];
  {
    const short* w0 = wt + (cg * 32 + cl) * D_ + gr * 8;
    const short* w1 = w0 + 16 * D_;
#pragma unroll
    for (int kf = 0; kf < 8; ++kf) {
      bfr0[kf] = *(const short8*)(w0 + kf * 32);
      bfr1[kf] = *(const short8*)(w1 + kf * 32);
    }
  }
  const float bv0 = bias[cg * 32 + cl], bv1 = bias[cg * 32 + 16 + cl];
  const float uv0 = u[cg * 32 + cl],    uv1 = u[cg * 32 + 16 + cl];

  const int block0 = blockIdx.x * (TILES_PER_BLOCK * BM);  // global row base

  // ---- staging assignment: thread -> row sr, float cols sc..sc+15
  const int sr = tid >> 4;
  const int sc = (tid & 15) * 16;
  const int swzw = (sr & 7) << 4;
  const int wb0 = sr * 512 + ((sc * 2) ^ swzw);
  const int wb1 = sr * 512 + ((sc * 2 + 16) ^ swzw);

  // prologue: stage tile 0 into buf 0
  {
    const float* xs = x + ((size_t)block0 + sr) * D_ + sc;
    f4 g0 = *(const f4*)(xs + 0), g1 = *(const f4*)(xs + 4);
    f4 g2 = *(const f4*)(xs + 8), g3 = *(const f4*)(xs + 12);
    short8 s0, s1;
    s0[0]=f2bf(g0[0]); s0[1]=f2bf(g0[1]); s0[2]=f2bf(g0[2]); s0[3]=f2bf(g0[3]);
    s0[4]=f2bf(g1[0]); s0[5]=f2bf(g1[1]); s0[6]=f2bf(g1[2]); s0[7]=f2bf(g1[3]);
    s1[0]=f2bf(g2[0]); s1[1]=f2bf(g2[1]); s1[2]=f2bf(g2[2]); s1[3]=f2bf(g2[3]);
    s1[4]=f2bf(g3[0]); s1[5]=f2bf(g3[1]); s1[6]=f2bf(g3[2]); s1[7]=f2bf(g3[3]);
    char* b0 = (char*)&lsA[0][0];
    *(short8*)(b0 + wb0) = s0;
    *(short8*)(b0 + wb1) = s1;
  }

  const int r0byte = (rg * 32 + cl) * 512;
  const int r1byte = r0byte + 16 * 512;
  const int gb = gr * 16;

  for (int t = 0; t < TILES_PER_BLOCK; ++t) {
    const int t0 = block0 + t * BM;
    const int tile_idx = blockIdx.x * TILES_PER_BLOCK + t;

    // issue next tile's global loads EARLY (hidden under MFMA + epilogue)
    f4 n0, n1, n2, n3;
    if (t < TILES_PER_BLOCK - 1) {
      const float* xn = x + ((size_t)t0 + BM + sr) * D_ + sc;
      n0 = *(const f4*)(xn + 0); n1 = *(const f4*)(xn + 4);
      n2 = *(const f4*)(xn + 8); n3 = *(const f4*)(xn + 12);
    }

    __syncthreads();   // buf[t&1] writes (from prev iter) visible

    const char* A = (const char*)&lsA[t & 1][0];
    f32x4 acc00 = {0.f,0.f,0.f,0.f}, acc01 = {0.f,0.f,0.f,0.f};
    f32x4 acc10 = {0.f,0.f,0.f,0.f}, acc11 = {0.f,0.f,0.f,0.f};
#pragma unroll
    for (int kf = 0; kf < 8; ++kf) {
      const int co = (kf * 64 + gb) ^ swzr;
      short8 a0 = *(const short8*)(A + r0byte + co);
      short8 a1 = *(const short8*)(A + r1byte + co);
      acc00 = __builtin_amdgcn_mfma_f32_16x16x32_bf16(a0, bfr0[kf], acc00, 0, 0, 0);
      acc01 = __builtin_amdgcn_mfma_f32_16x16x32_bf16(a0, bfr1[kf], acc01, 0, 0, 0);
      acc10 = __builtin_amdgcn_mfma_f32_16x16x32_bf16(a1, bfr0[kf], acc10, 0, 0, 0);
      acc11 = __builtin_amdgcn_mfma_f32_16x16x32_bf16(a1, bfr1[kf], acc11, 0, 0, 0);
    }

    // per-wave col-partial scores (32 cols), reduce over 16 lanes
    float q0[4], q1[4];
#pragma unroll
    for (int j = 0; j < 4; ++j) {
      q0[j] = fast_tanh(acc00[j] + bv0) * uv0 + fast_tanh(acc01[j] + bv1) * uv1;
      q1[j] = fast_tanh(acc10[j] + bv0) * uv0 + fast_tanh(acc11[j] + bv1) * uv1;
    }
#pragma unroll
    for (int m = 1; m < 16; m <<= 1) {
#pragma unroll
      for (int j = 0; j < 4; ++j) {
        q0[j] += __shfl_xor(q0[j], m);
        q1[j] += __shfl_xor(q1[j], m);
      }
    }
    if (cl == 0) {
      const int rb = rg * 32 + gr * 4;
#pragma unroll
      for (int j = 0; j < 4; ++j) {
        score_part[rb + j][cg]      = q0[j];
        score_part[rb + 16 + j][cg] = q1[j];
      }
    }
    __syncthreads();   // score_part complete

    if (tid < 64) {
      float s = score_part[tid][0] + score_part[tid][1] + score_part[tid][2] +
                score_part[tid][3] + score_part[tid][4] + score_part[tid][5] +
                score_part[tid][6] + score_part[tid][7];
      float mx = s;
#pragma unroll
      for (int off = 32; off >= 1; off >>= 1) mx = fmaxf(mx, __shfl_xor(mx, off));
      float e = __expf(s - mx);
      e_lds[tid] = e;
      float l = e;
#pragma unroll
      for (int off = 32; off >= 1; off >>= 1) l += __shfl_xor(l, off);
      ws_scores[t0 + tid] = s;
      if (tid == 0) { ws_m[tile_idx] = mx; ws_l[tile_idx] = l; }
    }
    __syncthreads();   // e_lds ready

    // context partial: quarter q handles 16 rows for all 256 cols (x is L2-hot)
    {
      const int qq = tid >> 8, d = tid & 255;
      const float* xp = x + ((size_t)t0 + qq * 16) * D_ + d;
      float c = 0.f;
#pragma unroll
      for (int s2 = 0; s2 < 16; ++s2)
        c = fmaf(e_lds[qq * 16 + s2], xp[(size_t)s2 * D_], c);
      ctx_part[qq][d] = c;
    }
    __syncthreads();   // ctx_part complete (also: all reads of buf[(t+1)&1] long done)
    if (tid < 256)
      ws_c[(size_t)tile_idx * D_ + tid] =
          ctx_part[0][tid] + ctx_part[1][tid] + ctx_part[2][tid] + ctx_part[3][tid];

    // stage next tile into the other buffer (visibility via next iter's top barrier)
    if (t < TILES_PER_BLOCK - 1) {
      short8 s0, s1;
      s0[0]=f2bf(n0[0]); s0[1]=f2bf(n0[1]); s0[2]=f2bf(n0[2]); s0[3]=f2bf(n0[3]);
      s0[4]=f2bf(n1[0]); s0[5]=f2bf(n1[1]); s0[6]=f2bf(n1[2]); s0[7]=f2bf(n1[3]);
      s1[0]=f2bf(n2[0]); s1[1]=f2bf(n2[1]); s1[2]=f2bf(n2[2]); s1[3]=f2bf(n2[3]);
      s1[4]=f2bf(n3[0]); s1[5]=f2bf(n3[1]); s1[6]=f2bf(n3[2]); s1[7]=f2bf(n3[3]);
      char* bn = (char*)&lsA[(t + 1) & 1][0];
      *(short8*)(bn + wb0) = s0;
      *(short8*)(bn + wb1) = s1;
    }
  }
}

// Kernel 2: per-batch combine of 64 tile partials -> context out + (M, L)
__global__ void k_combine(const float* __restrict__ ws_m, const float* __restrict__ ws_l,
                          const float* __restrict__ ws_c, float* __restrict__ out_ctx,
                          float* __restrict__ ws_M, float* __restrict__ ws_L) {
  int b = blockIdx.x, d = threadIdx.x;
  float M = -1e30f;
#pragma unroll
  for (int i = 0; i < BLKS_PER_B; ++i) M = fmaxf(M, ws_m[b * BLKS_PER_B + i]);
  float L = 0.f, c = 0.f;
#pragma unroll 4
  for (int i = 0; i < BLKS_PER_B; ++i) {
    float f = __expf(ws_m[b * BLKS_PER_B + i] - M);
    L += ws_l[b * BLKS_PER_B + i] * f;
    c += ws_c[(size_t)(b * BLKS_PER_B + i) * D_ + d] * f;
  }
  out_ctx[b * D_ + d] = c / L;
  if (d == 0) { ws_M[b] = M; ws_L[b] = L; }
}

// Kernel 3: weights[b,s] = exp(score - M_b) / L_b
__global__ void k_weights(const float* __restrict__ ws_scores, const float* __restrict__ ws_M,
                          const float* __restrict__ ws_L, float* __restrict__ out_w) {
  int idx = blockIdx.x * 256 + threadIdx.x;
  int b = idx >> 12;
  out_w[idx] = __expf(ws_scores[idx] - ws_M[b]) / ws_L[b];
}

extern "C" void kernel_launch(void* const* d_in, const int* in_sizes, int n_in,
                              void* d_out, int out_size, void* d_ws, size_t ws_size,
                              hipStream_t stream) {
  (void)in_sizes; (void)n_in; (void)out_size; (void)ws_size;
  const float* x    = (const float*)d_in[0];
  const float* W    = (const float*)d_in[1];
  const float* bias = (const float*)d_in[2];
  const float* u    = (const float*)d_in[3];
  float* out_ctx = (float*)d_out;                 // [64,256]
  float* out_w   = (float*)d_out + B_ * D_;       // [64,4096]

  char* ws = (char*)d_ws;
  short* wt        = (short*)(ws + 0);            // 131072 B
  float* ws_scores = (float*)(ws + 131072);       // 1048576 B
  float* ws_m      = (float*)(ws + 1179648);      // 16384 B
  float* ws_l      = (float*)(ws + 1196032);      // 16384 B
  float* ws_c      = (float*)(ws + 1212416);      // 4194304 B
  float* ws_M      = (float*)(ws + 5406720);      // 256 B
  float* ws_L      = (float*)(ws + 5406976);      // 256 B

  hipLaunchKernelGGL(k_pack, dim3(16), dim3(256), 0, stream, W, wt);
  hipLaunchKernelGGL(k_scores, dim3(GRID), dim3(TPB), 0, stream,
                     x, wt, bias, u, ws_scores, ws_m, ws_l, ws_c);
  hipLaunchKernelGGL(k_combine, dim3(B_), dim3(256), 0, stream,
                     ws_m, ws_l, ws_c, out_ctx, ws_M, ws_L);
  hipLaunchKernelGGL(k_weights, dim3(B_ * S_ / 256), dim3(256), 0, stream,
                     ws_scores, ws_M, ws_L, out_w);
}